// Round 1
// baseline (2484.968 us; speedup 1.0000x reference)
//
#include <hip/hip_runtime.h>

#define S 2048
#define D 64
#define TQ 64
#define TK 64
#define NKT (S / TK)
#define KSTR 68  // padded stride for K/P union buffer

// LDS: Qs 16384 + KPs 17408 + Vs 16384 = 50176 B -> 3 blocks/CU
__launch_bounds__(256, 3)
__global__ void attn_fused(const float* __restrict__ Q,
                           const float* __restrict__ K,
                           const float* __restrict__ V,
                           const int* __restrict__ mask,
                           float* __restrict__ out,
                           float* __restrict__ attn) {
  __shared__ float Qs[D][D];       // [d][row]   (transposed Q tile)
  __shared__ float KPs[TK][KSTR];  // Ks[d][key] during scores, Ps[key][row] during PV
  __shared__ float Vs[TK][D];      // [key][d]

  const int tid = threadIdx.x;
  const int tc = tid & 15;   // key-block / d-block index (0..15)
  const int tr = tid >> 4;   // row-block index (0..15)
  const int head = blockIdx.y;   // b*16 + h
  const int b = head >> 4;
  const int q0 = blockIdx.x * TQ;

  const float* Qg = Q + ((size_t)head * S + q0) * D;
  const float* Kg = K + (size_t)head * S * D;
  const float* Vg = V + (size_t)head * S * D;
  const int* mg = mask + b * S;

  // ---- stage Q transposed: Qs[d][row] ----
  {
    const int dc = (tid & 15) * 4;
    const int rr = tid >> 4;
#pragma unroll
    for (int rep = 0; rep < 4; ++rep) {
      const int row = rep * 16 + rr;
      const float4 v = *(const float4*)(Qg + row * D + dc);
      Qs[dc + 0][row] = v.x;
      Qs[dc + 1][row] = v.y;
      Qs[dc + 2][row] = v.z;
      Qs[dc + 3][row] = v.w;
    }
  }

  float m_i[4], l_i[4];
#pragma unroll
  for (int i = 0; i < 4; ++i) { m_i[i] = -1e30f; l_i[i] = 0.0f; }

  // =============== pass 1: online row max & sum ===============
  for (int kt = 0; kt < NKT; ++kt) {
    __syncthreads();
    {  // stage K transposed: KPs[d][key]
      const float* Kt = Kg + (size_t)kt * TK * D;
      const int dc = (tid & 15) * 4;
      const int rr = tid >> 4;
#pragma unroll
      for (int rep = 0; rep < 4; ++rep) {
        const int kk = rep * 16 + rr;
        const float4 v = *(const float4*)(Kt + kk * D + dc);
        KPs[dc + 0][kk] = v.x;
        KPs[dc + 1][kk] = v.y;
        KPs[dc + 2][kk] = v.z;
        KPs[dc + 3][kk] = v.w;
      }
    }
    __syncthreads();

    float s[4][4];
#pragma unroll
    for (int i = 0; i < 4; ++i)
#pragma unroll
      for (int j = 0; j < 4; ++j) s[i][j] = 0.0f;

#pragma unroll 8
    for (int d = 0; d < D; ++d) {
      const float4 qv = *(const float4*)&Qs[d][tr * 4];
      const float4 kv = *(const float4*)&KPs[d][tc * 4];
      const float qa[4] = {qv.x, qv.y, qv.z, qv.w};
      const float ka[4] = {kv.x, kv.y, kv.z, kv.w};
#pragma unroll
      for (int i = 0; i < 4; ++i)
#pragma unroll
        for (int j = 0; j < 4; ++j) s[i][j] = fmaf(qa[i], ka[j], s[i][j]);
    }

    const int4 mk = *(const int4*)(mg + kt * TK + tc * 4);
    const int ma[4] = {mk.x, mk.y, mk.z, mk.w};
#pragma unroll
    for (int i = 0; i < 4; ++i)
#pragma unroll
      for (int j = 0; j < 4; ++j)
        s[i][j] = ma[j] ? s[i][j] * 0.125f : -1e30f;

#pragma unroll
    for (int i = 0; i < 4; ++i) {
      float tmax = fmaxf(fmaxf(s[i][0], s[i][1]), fmaxf(s[i][2], s[i][3]));
#pragma unroll
      for (int off = 1; off < 16; off <<= 1)
        tmax = fmaxf(tmax, __shfl_xor(tmax, off));
      const float mnew = fmaxf(m_i[i], tmax);
      float tsum = __expf(s[i][0] - mnew) + __expf(s[i][1] - mnew) +
                   __expf(s[i][2] - mnew) + __expf(s[i][3] - mnew);
#pragma unroll
      for (int off = 1; off < 16; off <<= 1)
        tsum += __shfl_xor(tsum, off);
      l_i[i] = l_i[i] * __expf(m_i[i] - mnew) + tsum;
      m_i[i] = mnew;
    }
  }

  float inv_l[4];
#pragma unroll
  for (int i = 0; i < 4; ++i) inv_l[i] = 1.0f / l_i[i];

  float o[4][4];
#pragma unroll
  for (int i = 0; i < 4; ++i)
#pragma unroll
    for (int j = 0; j < 4; ++j) o[i][j] = 0.0f;

  float* attn_base = attn + ((size_t)head * S + q0) * S;

  // =============== pass 2: p = exp(s-m)/l, write attn, O += P.V ===============
  for (int kt = 0; kt < NKT; ++kt) {
    __syncthreads();
    {  // stage K transposed + V natural
      const float* Kt = Kg + (size_t)kt * TK * D;
      const float* Vt = Vg + (size_t)kt * TK * D;
      const int dc = (tid & 15) * 4;
      const int rr = tid >> 4;
#pragma unroll
      for (int rep = 0; rep < 4; ++rep) {
        const int kk = rep * 16 + rr;
        const float4 v = *(const float4*)(Kt + kk * D + dc);
        KPs[dc + 0][kk] = v.x;
        KPs[dc + 1][kk] = v.y;
        KPs[dc + 2][kk] = v.z;
        KPs[dc + 3][kk] = v.w;
        const float4 vv = *(const float4*)(Vt + kk * D + dc);
        *(float4*)&Vs[kk][dc] = vv;
      }
    }
    __syncthreads();

    float s[4][4];
#pragma unroll
    for (int i = 0; i < 4; ++i)
#pragma unroll
      for (int j = 0; j < 4; ++j) s[i][j] = 0.0f;

#pragma unroll 8
    for (int d = 0; d < D; ++d) {
      const float4 qv = *(const float4*)&Qs[d][tr * 4];
      const float4 kv = *(const float4*)&KPs[d][tc * 4];
      const float qa[4] = {qv.x, qv.y, qv.z, qv.w};
      const float ka[4] = {kv.x, kv.y, kv.z, kv.w};
#pragma unroll
      for (int i = 0; i < 4; ++i)
#pragma unroll
        for (int j = 0; j < 4; ++j) s[i][j] = fmaf(qa[i], ka[j], s[i][j]);
    }

    const int4 mk = *(const int4*)(mg + kt * TK + tc * 4);
    const int ma[4] = {mk.x, mk.y, mk.z, mk.w};
    float p[4][4];
#pragma unroll
    for (int i = 0; i < 4; ++i)
#pragma unroll
      for (int j = 0; j < 4; ++j) {
        const float sv = ma[j] ? s[i][j] * 0.125f : -1e30f;
        p[i][j] = __expf(sv - m_i[i]) * inv_l[i];
      }

    // coalesced attn store: row-major, 4 keys per float4
#pragma unroll
    for (int i = 0; i < 4; ++i) {
      const float4 pv = {p[i][0], p[i][1], p[i][2], p[i][3]};
      *(float4*)(attn_base + (size_t)(tr * 4 + i) * S + kt * TK + tc * 4) = pv;
    }

    __syncthreads();  // all waves done reading KPs-as-K before overwriting with P

    // write P transposed into the K buffer: Ps[key][row]
#pragma unroll
    for (int j = 0; j < 4; ++j) {
      const float4 pc = {p[0][j], p[1][j], p[2][j], p[3][j]};
      *(float4*)&KPs[tc * 4 + j][tr * 4] = pc;
    }
    // (written/read by the same 16-lane group -> same wave, in-order LDS; no barrier needed)

#pragma unroll 8
    for (int k = 0; k < TK; ++k) {
      const float4 pp = *(const float4*)&KPs[k][tr * 4];
      const float4 vv = *(const float4*)&Vs[k][tc * 4];
      const float pa[4] = {pp.x, pp.y, pp.z, pp.w};
      const float va[4] = {vv.x, vv.y, vv.z, vv.w};
#pragma unroll
      for (int i = 0; i < 4; ++i)
#pragma unroll
        for (int j = 0; j < 4; ++j) o[i][j] = fmaf(pa[i], va[j], o[i][j]);
    }
  }

  // write output: out[head][q0+row][d]
#pragma unroll
  for (int i = 0; i < 4; ++i) {
    const float4 ov = {o[i][0], o[i][1], o[i][2], o[i][3]};
    *(float4*)(out + ((size_t)head * S + q0 + tr * 4 + i) * D + tc * 4) = ov;
  }
}

extern "C" void kernel_launch(void* const* d_in, const int* in_sizes, int n_in,
                              void* d_out, int out_size, void* d_ws, size_t ws_size,
                              hipStream_t stream) {
  (void)in_sizes; (void)n_in; (void)out_size; (void)d_ws; (void)ws_size;
  const float* Q = (const float*)d_in[0];
  const float* K = (const float*)d_in[1];
  const float* V = (const float*)d_in[2];
  const int* mask = (const int*)d_in[3];
  float* out = (float*)d_out;
  float* attn = out + (size_t)4 * 16 * 2048 * 64;  // outputs concatenated: output, attn
  dim3 grid(S / TQ, 4 * 16);
  attn_fused<<<grid, dim3(256), 0, stream>>>(Q, K, V, mask, out, attn);
}